// Round 2
// baseline (7695.871 us; speedup 1.0000x reference)
//
#include <hip/hip_runtime.h>
#include <math.h>

#define NB 4
#define NC 64
#define NH 128
#define NW 128
#define TH 256
#define TW 256
#define HID 256
#define INDIM 84
#define ROWS 32      // rows per block = PIX * 4 ensembles
#define PIX 8
#define ASTRIDE 260  // padded LDS row stride (floats), %4==0 for float4

// One dense layer, neuron-major: thread j computes neuron j for all ROWS rows.
// Weights Wg are (K, HID) row-major f32; activations read as wave-uniform
// float4 broadcasts from LDS (conflict-free). Next-k4 weights prefetched.
template<int K, bool RELU>
__device__ __forceinline__ void dense(const float (*in)[ASTRIDE], float (*outp)[ASTRIDE],
                                      const float* __restrict__ Wg,
                                      const float* __restrict__ bg, int j)
{
  float acc[ROWS];
  const float bb = bg[j];
#pragma unroll
  for (int r = 0; r < ROWS; ++r) acc[r] = bb;

  float wv0 = Wg[0 * HID + j];
  float wv1 = Wg[1 * HID + j];
  float wv2 = Wg[2 * HID + j];
  float wv3 = Wg[3 * HID + j];
#pragma unroll 1
  for (int k4 = 0; k4 < K / 4; ++k4) {
    float n0 = 0.f, n1 = 0.f, n2 = 0.f, n3 = 0.f;
    if (k4 + 1 < K / 4) {           // prefetch next 4 weights (hide L2 latency)
      n0 = Wg[(k4 * 4 + 4) * HID + j];
      n1 = Wg[(k4 * 4 + 5) * HID + j];
      n2 = Wg[(k4 * 4 + 6) * HID + j];
      n3 = Wg[(k4 * 4 + 7) * HID + j];
    }
#pragma unroll
    for (int r = 0; r < ROWS; ++r) {
      const float4 a = *(const float4*)(&in[r][k4 * 4]);
      float s = acc[r];
      s = fmaf(a.x, wv0, s);
      s = fmaf(a.y, wv1, s);
      s = fmaf(a.z, wv2, s);
      s = fmaf(a.w, wv3, s);
      acc[r] = s;
    }
    wv0 = n0; wv1 = n1; wv2 = n2; wv3 = n3;
  }
#pragma unroll
  for (int r = 0; r < ROWS; ++r) outp[r][j] = RELU ? fmaxf(acc[r], 0.0f) : acc[r];
}

__global__ __launch_bounds__(256, 2) void inr2d_fused(
    const float* __restrict__ feat,
    const float* __restrict__ w0, const float* __restrict__ b0,
    const float* __restrict__ w1, const float* __restrict__ b1,
    const float* __restrict__ w2, const float* __restrict__ b2,
    const float* __restrict__ w3, const float* __restrict__ b3,
    float* __restrict__ out)
{
  __shared__ float actA[ROWS][ASTRIDE];
  __shared__ float actB[ROWS][ASTRIDE];
  __shared__ float area_s[ROWS];
  __shared__ float pred_s[ROWS][3];

  const int t = threadIdx.x;
  const int blk = blockIdx.x;

  // ---------- phase 0: build the 84-dim input rows ----------
  {
    const int r = t >> 3;       // row 0..31
    const int sub = t & 7;      // 8 threads per row
    const int pix = r >> 2;     // 0..7
    const int e = r & 3;        // ensemble: (vx,vy) = (e&2? +:-, e&1? +:-)
    const int gp = blk * PIX + pix;
    const int b = gp >> 16;           // TH*TW = 65536
    const int rem = gp & 65535;
    const int oy = rem >> 8;
    const int ox = rem & 255;

    const float cy = (2.0f * oy + 1.0f) / (float)TH - 1.0f;
    const float cx = (2.0f * ox + 1.0f) / (float)TW - 1.0f;
    const float vx = (e & 2) ? 1.0f : -1.0f;
    const float vy = (e & 1) ? 1.0f : -1.0f;
    const float rr = 1.0f / (float)NH;  // rx = ry = 1/128

    float c0 = cy + vx * rr + 1e-6f;
    float c1 = cx + vy * rr + 1e-6f;
    c0 = fminf(fmaxf(c0, -1.0f + 1e-6f), 1.0f - 1e-6f);
    c1 = fminf(fmaxf(c1, -1.0f + 1e-6f), 1.0f - 1e-6f);

    const float ix = (c1 + 1.0f) * 0.5f * (float)(NW - 1);
    const float iy = (c0 + 1.0f) * 0.5f * (float)(NH - 1);
    const float x0f = floorf(ix), y0f = floorf(iy);
    int x0 = (int)x0f; x0 = max(0, min(x0, NW - 1));
    int x1 = min(x0 + 1, NW - 1);
    int y0 = (int)y0f; y0 = max(0, min(y0, NH - 1));
    int y1 = min(y0 + 1, NH - 1);
    const float wx1 = ix - x0f, wx0 = 1.0f - wx1;
    const float wy1 = iy - y0f, wy0 = 1.0f - wy1;
    const float w00 = wy0 * wx0, w01 = wy0 * wx1, w10 = wy1 * wx0, w11 = wy1 * wx1;

    const float* fb = feat + (size_t)b * NC * NH * NW;
    const int i00 = y0 * NW + x0, i01 = y0 * NW + x1;
    const int i10 = y1 * NW + x0, i11 = y1 * NW + x1;
#pragma unroll
    for (int i = 0; i < 8; ++i) {
      const int c = sub * 8 + i;
      const float* fc = fb + (size_t)c * (NH * NW);
      const float v = w00 * fc[i00] + w01 * fc[i01] +
                      w10 * fc[i10] + w11 * fc[i11];
      actA[r][c] = v;
    }
    if (sub == 0) {
      // analytic q_coord (bilinear interp of the coord channels)
      const float qy = -1.0f + 1.0f / NH + (2.0f / NH) * (wy0 * (float)y0 + wy1 * (float)y1);
      const float qx = -1.0f + 1.0f / NW + (2.0f / NW) * (wx0 * (float)x0 + wx1 * (float)x1);
      const float rely = (cy - qy) * (float)NH;
      const float relx = (cx - qx) * (float)NW;
      actA[r][64] = rely;
      actA[r][65] = relx;
#pragma unroll
      for (int l = 0; l < 4; ++l) {
        const float f = (float)(1 << l) * (float)M_PI;
        actA[r][66 + l] = sinf(cy * f);
        actA[r][70 + l] = cosf(cy * f);
        actA[r][74 + l] = sinf(cx * f);
        actA[r][78 + l] = cosf(cx * f);
      }
      actA[r][82] = 2.0f / (float)TH * (float)NH;  // rel_cell = 1.0
      actA[r][83] = 2.0f / (float)TW * (float)NW;  // rel_cell = 1.0
      area_s[r] = fabsf(rely * relx) + 1e-9f;
    }
  }
  __syncthreads();

  // ---------- layers 0..2 ----------
  dense<INDIM, true>(actA, actB, w0, b0, t);
  __syncthreads();
  dense<HID, true>(actB, actA, w1, b1, t);
  __syncthreads();
  dense<HID, true>(actA, actB, w2, b2, t);
  __syncthreads();

  // ---------- layer 3: 256 -> 3 ----------
  if (t < 96) {
    const int r = t / 3;
    const int o = t - r * 3;
    float acc = b3[o];
#pragma unroll 1
    for (int k4 = 0; k4 < HID / 4; ++k4) {
      const float4 a = *(const float4*)(&actB[r][k4 * 4]);
      acc = fmaf(a.x, w3[(k4 * 4 + 0) * 3 + o], acc);
      acc = fmaf(a.y, w3[(k4 * 4 + 1) * 3 + o], acc);
      acc = fmaf(a.z, w3[(k4 * 4 + 2) * 3 + o], acc);
      acc = fmaf(a.w, w3[(k4 * 4 + 3) * 3 + o], acc);
    }
    pred_s[r][o] = acc;
  }
  __syncthreads();

  // ---------- ensemble combine: pred_e weighted by area[3-e]/tot ----------
  if (t < 24) {
    const int pix = t / 3;
    const int o = t - pix * 3;
    const int gp = blk * PIX + pix;
    const int b = gp >> 16;
    const int rem = gp & 65535;
    const int oy = rem >> 8;
    const int ox = rem & 255;
    const int r0 = pix * 4;
    const float a0 = area_s[r0 + 0], a1 = area_s[r0 + 1];
    const float a2 = area_s[r0 + 2], a3 = area_s[r0 + 3];
    const float tot = a0 + a1 + a2 + a3;
    const float v = pred_s[r0 + 0][o] * a3 + pred_s[r0 + 1][o] * a2 +
                    pred_s[r0 + 2][o] * a1 + pred_s[r0 + 3][o] * a0;
    out[(((size_t)b * 3 + o) << 16) + (oy << 8) + ox] = v / tot;
  }
}

extern "C" void kernel_launch(void* const* d_in, const int* in_sizes, int n_in,
                              void* d_out, int out_size, void* d_ws, size_t ws_size,
                              hipStream_t stream) {
  const float* feat = (const float*)d_in[0];
  const float* w0 = (const float*)d_in[1];
  const float* b0 = (const float*)d_in[2];
  const float* w1 = (const float*)d_in[3];
  const float* b1 = (const float*)d_in[4];
  const float* w2 = (const float*)d_in[5];
  const float* b2 = (const float*)d_in[6];
  const float* w3 = (const float*)d_in[7];
  const float* b3 = (const float*)d_in[8];
  float* out = (float*)d_out;

  const int blocks = (NB * TH * TW) / PIX;  // 32768
  inr2d_fused<<<blocks, 256, 0, stream>>>(feat, w0, b0, w1, b1, w2, b2, w3, b3, out);
}

// Round 3
// 824.210 us; speedup vs baseline: 9.3373x; 9.3373x over previous
//
#include <hip/hip_runtime.h>
#include <math.h>

#define NB 4
#define NH 128
#define NW 128
#define TH 256
#define TW 256
#define AST 264          // act row stride in f16 elems (528 B): 2-way bank alias only
#define K0 96            // layer0 K padded 84->96 (zeros)

typedef _Float16 f16;
typedef f16  f16x8 __attribute__((ext_vector_type(8)));
typedef f16  f16x4v __attribute__((ext_vector_type(4)));
typedef float f32x4 __attribute__((ext_vector_type(4)));

// ws layout (f16 elems): W0t[256][96] | W1t[256][256] | W2t[256][256] | W3t[16][256]
#define OFF_W1 24576
#define OFF_W2 (OFF_W1 + 65536)
#define OFF_W3 (OFF_W2 + 65536)
#define WS_ELEMS (OFF_W3 + 4096)

__global__ void cvt_weights(const float* __restrict__ w0, const float* __restrict__ w1,
                            const float* __restrict__ w2, const float* __restrict__ w3,
                            f16* __restrict__ ws) {
  const int i = blockIdx.x * 256 + threadIdx.x;
  if (i < 24576) {                       // W0t[n][k] = w0[k][n], k<84 else 0
    const int n = i / 96, k = i - n * 96;
    ws[i] = (k < 84) ? (f16)w0[k * 256 + n] : (f16)0.f;
  } else if (i < OFF_W2) {               // W1t[n][k] = w1[k][n]
    const int j = i - OFF_W1; const int n = j >> 8, k = j & 255;
    ws[i] = (f16)w1[k * 256 + n];
  } else if (i < OFF_W3) {               // W2t
    const int j = i - OFF_W2; const int n = j >> 8, k = j & 255;
    ws[i] = (f16)w2[k * 256 + n];
  } else if (i < WS_ELEMS) {             // W3t[n][k] = w3[k][n], n<3 else 0
    const int j = i - OFF_W3; const int n = j >> 8, k = j & 255;
    ws[i] = (n < 3) ? (f16)w3[k * 3 + n] : (f16)0.f;
  }
}

// One 256-wide layer on matrix cores. Wave tile: M=64 (all block rows) x N=64.
// A-operand = weights Wt[n][k] (global, L2-hot, per-wave-private slice, dbuf'd).
// B-operand = activations actIn[m][k] (LDS). D[n][m] -> relu -> f16 ->
// actOut[m][n] as 8B ds_write (4 consecutive n per lane are contiguous).
template<int K>
__device__ __forceinline__ void dense_layer(const f16* __restrict__ Wt,
                                            const float* __restrict__ bias,
                                            const f16* actIn, f16* actOut,
                                            int w, int l) {
  constexpr int NK = K / 32;
  const int nl = l & 15, kq = l >> 4;
  const f16* Abase = Wt + (size_t)(w * 64 + nl) * K + kq * 8;
  const f16* Bbase = actIn + nl * AST + kq * 8;

  f32x4 acc[4][4];
#pragma unroll
  for (int nf = 0; nf < 4; ++nf) {
    const float4 b4 = *(const float4*)(bias + w * 64 + nf * 16 + kq * 4);
    f32x4 a; a[0] = b4.x; a[1] = b4.y; a[2] = b4.z; a[3] = b4.w;
#pragma unroll
    for (int mf = 0; mf < 4; ++mf) acc[nf][mf] = a;
  }

  f16x8 A0[4], A1[4], B[4];
#pragma unroll
  for (int nf = 0; nf < 4; ++nf) A0[nf] = *(const f16x8*)(Abase + nf * 16 * K);

#pragma unroll
  for (int ks = 0; ks < NK; ++ks) {
    f16x8* cur = (ks & 1) ? A1 : A0;
    f16x8* nxt = (ks & 1) ? A0 : A1;
    if (ks + 1 < NK) {
#pragma unroll
      for (int nf = 0; nf < 4; ++nf)
        nxt[nf] = *(const f16x8*)(Abase + (ks + 1) * 32 + nf * 16 * K);
    }
#pragma unroll
    for (int mf = 0; mf < 4; ++mf)
      B[mf] = *(const f16x8*)(Bbase + ks * 32 + mf * 16 * AST);
#pragma unroll
    for (int nf = 0; nf < 4; ++nf)
#pragma unroll
      for (int mf = 0; mf < 4; ++mf)
        acc[nf][mf] = __builtin_amdgcn_mfma_f32_16x16x32_f16(cur[nf], B[mf], acc[nf][mf], 0, 0, 0);
  }

#pragma unroll
  for (int nf = 0; nf < 4; ++nf)
#pragma unroll
    for (int mf = 0; mf < 4; ++mf) {
      f16x4v o;
      o[0] = (f16)fmaxf(acc[nf][mf][0], 0.f);
      o[1] = (f16)fmaxf(acc[nf][mf][1], 0.f);
      o[2] = (f16)fmaxf(acc[nf][mf][2], 0.f);
      o[3] = (f16)fmaxf(acc[nf][mf][3], 0.f);
      *(f16x4v*)(actOut + (mf * 16 + nl) * AST + w * 64 + nf * 16 + kq * 4) = o;
    }
}

__global__ __launch_bounds__(256, 2) void inr2d_mfma(
    const float* __restrict__ feat,
    const float* __restrict__ b0, const float* __restrict__ b1,
    const float* __restrict__ b2, const float* __restrict__ b3,
    const f16* __restrict__ ws, float* __restrict__ out)
{
  __shared__ f16 actA[64][AST];
  __shared__ f16 actB[64][AST];
  __shared__ float area_s[64];
  __shared__ float pred_s[64][4];

  const int t = threadIdx.x;
  // XCD-chunked swizzle (16384 % 8 == 0 -> bijective)
  const int blk = ((blockIdx.x & 7) << 11) | (blockIdx.x >> 3);

  // ---------- phase 0: build 64 input rows (16 px x 4 ensembles), f16 ----------
  {
    const int r = t >> 2, sub = t & 3;     // 4 threads per row, 16 ch each
    const int pix = r >> 2, e = r & 3;
    const int gp = blk * 16 + pix;
    const int b = gp >> 16, rem = gp & 65535;
    const int oy = rem >> 8, ox = rem & 255;

    const float cy = (2.0f * oy + 1.0f) / (float)TH - 1.0f;
    const float cx = (2.0f * ox + 1.0f) / (float)TW - 1.0f;
    const float vx = (e & 2) ? 1.0f : -1.0f;
    const float vy = (e & 1) ? 1.0f : -1.0f;
    const float rr = 1.0f / (float)NH;

    float c0 = fminf(fmaxf(cy + vx * rr + 1e-6f, -1.0f + 1e-6f), 1.0f - 1e-6f);
    float c1 = fminf(fmaxf(cx + vy * rr + 1e-6f, -1.0f + 1e-6f), 1.0f - 1e-6f);

    const float ix = (c1 + 1.0f) * 0.5f * (float)(NW - 1);
    const float iy = (c0 + 1.0f) * 0.5f * (float)(NH - 1);
    const float x0f = floorf(ix), y0f = floorf(iy);
    int x0 = (int)x0f; x0 = max(0, min(x0, NW - 1));
    int x1 = min(x0 + 1, NW - 1);
    int y0 = (int)y0f; y0 = max(0, min(y0, NH - 1));
    int y1 = min(y0 + 1, NH - 1);
    const float wx1 = ix - x0f, wx0 = 1.0f - wx1;
    const float wy1 = iy - y0f, wy0 = 1.0f - wy1;
    const float w00 = wy0 * wx0, w01 = wy0 * wx1, w10 = wy1 * wx0, w11 = wy1 * wx1;

    const float* fb = feat + (size_t)b * 64 * NH * NW;
    const int i00 = y0 * NW + x0, i01 = y0 * NW + x1;
    const int i10 = y1 * NW + x0, i11 = y1 * NW + x1;
#pragma unroll
    for (int i = 0; i < 16; ++i) {
      const int c = sub * 16 + i;
      const float* fc = fb + (size_t)c * (NH * NW);
      const float v = w00 * fc[i00] + w01 * fc[i01] + w10 * fc[i10] + w11 * fc[i11];
      actA[r][c] = (f16)v;
    }
    if (sub == 0) {
      const float qy = -1.0f + 1.0f / NH + (2.0f / NH) * (wy0 * (float)y0 + wy1 * (float)y1);
      const float qx = -1.0f + 1.0f / NW + (2.0f / NW) * (wx0 * (float)x0 + wx1 * (float)x1);
      const float rely = (cy - qy) * (float)NH;
      const float relx = (cx - qx) * (float)NW;
      actA[r][64] = (f16)rely;
      actA[r][65] = (f16)relx;
#pragma unroll
      for (int ll = 0; ll < 4; ++ll) {
        const float f = (float)(1 << ll) * (float)M_PI;
        actA[r][66 + ll] = (f16)sinf(cy * f);
        actA[r][70 + ll] = (f16)cosf(cy * f);
        actA[r][74 + ll] = (f16)sinf(cx * f);
        actA[r][78 + ll] = (f16)cosf(cx * f);
      }
      actA[r][82] = (f16)1.0f;   // rel_cell: 2/256*128 = 1.0
      actA[r][83] = (f16)1.0f;
#pragma unroll
      for (int z = 84; z < K0; ++z) actA[r][z] = (f16)0.f;  // K-pad
      area_s[r] = fabsf(rely * relx) + 1e-9f;
    }
  }
  __syncthreads();

  const int w = t >> 6, l = t & 63;

  dense_layer<K0 >(ws,           b0, &actA[0][0], &actB[0][0], w, l);
  __syncthreads();
  dense_layer<256>(ws + OFF_W1,  b1, &actB[0][0], &actA[0][0], w, l);
  __syncthreads();
  dense_layer<256>(ws + OFF_W2,  b2, &actA[0][0], &actB[0][0], w, l);
  __syncthreads();

  // ---------- layer 3: 256 -> 3 (wave w handles rows m = w*16 + lane) ----------
  {
    const int nl = l & 15, kq = l >> 4;
    const f16* Abase = ws + OFF_W3 + nl * 256 + kq * 8;
    const f16* Bbase = &actB[w * 16 + nl][0] + kq * 8;
    f32x4 acc = {0.f, 0.f, 0.f, 0.f};
#pragma unroll
    for (int ks = 0; ks < 8; ++ks) {
      f16x8 a = *(const f16x8*)(Abase + ks * 32);
      f16x8 b = *(const f16x8*)(Bbase + ks * 32);
      acc = __builtin_amdgcn_mfma_f32_16x16x32_f16(a, b, acc, 0, 0, 0);
    }
    if (l < 16) {
      float4 p;
      p.x = acc[0] + b3[0]; p.y = acc[1] + b3[1]; p.z = acc[2] + b3[2]; p.w = 0.f;
      *(float4*)(&pred_s[w * 16 + l][0]) = p;
    }
  }
  __syncthreads();

  // ---------- ensemble combine: pred_e weighted by area[3-e]/tot ----------
  if (t < 48) {
    const int pix = t / 3, o = t - pix * 3;
    const int gp = blk * 16 + pix;
    const int b = gp >> 16, rem = gp & 65535;
    const int oy = rem >> 8, ox = rem & 255;
    const int r0 = pix * 4;
    const float a0 = area_s[r0], a1 = area_s[r0 + 1], a2 = area_s[r0 + 2], a3 = area_s[r0 + 3];
    const float tot = a0 + a1 + a2 + a3;
    const float v = pred_s[r0][o] * a3 + pred_s[r0 + 1][o] * a2 +
                    pred_s[r0 + 2][o] * a1 + pred_s[r0 + 3][o] * a0;
    out[(((size_t)b * 3 + o) << 16) + (oy << 8) + ox] = v / tot;
  }
}

extern "C" void kernel_launch(void* const* d_in, const int* in_sizes, int n_in,
                              void* d_out, int out_size, void* d_ws, size_t ws_size,
                              hipStream_t stream) {
  const float* feat = (const float*)d_in[0];
  const float* w0 = (const float*)d_in[1];
  const float* b0 = (const float*)d_in[2];
  const float* w1 = (const float*)d_in[3];
  const float* b1 = (const float*)d_in[4];
  const float* w2 = (const float*)d_in[5];
  const float* b2 = (const float*)d_in[6];
  const float* w3 = (const float*)d_in[7];
  const float* b3 = (const float*)d_in[8];
  float* out = (float*)d_out;
  f16* ws = (f16*)d_ws;

  cvt_weights<<<(WS_ELEMS + 255) / 256, 256, 0, stream>>>(w0, w1, w2, w3, ws);
  inr2d_mfma<<<16384, 256, 0, stream>>>(feat, b0, b1, b2, b3, ws, out);
}